// Round 2
// baseline (1535.920 us; speedup 1.0000x reference)
//
#include <hip/hip_runtime.h>
#include <math.h>

#define EPS 1e-5f
#define N_GRAPHS 128

__device__ __forceinline__ float sigmoidf_(float x) {
    return __fdividef(1.0f, 1.0f + __expf(-x));
}

// ---------------------------------------------------------------------------
// Projection kernel v2: one 64-node tile per block; all 4 projections fused in
// a single k-loop (1 LDS read -> 64 FMA with wave-uniform s_load weights).
// Outputs staged through LDS and stored as coalesced float4 row writes:
//   Aq[n*64+o]=q, Av[n*64+o]=v, Bk[n*64+o]=k, AGG[n*64+o]=x@Ws+cb.
// NOTE: x may alias AGG (layer 1 in-place): safe because x rows are staged to
// LDS before any dump, and each block only writes its own rows.
// ---------------------------------------------------------------------------
template <int IN>
__global__ __launch_bounds__(256) void proj_kernel(
    const float* __restrict__ x,
    const float* __restrict__ Wk, const float* __restrict__ bk,
    const float* __restrict__ Wq, const float* __restrict__ bq,
    const float* __restrict__ Wv, const float* __restrict__ bv,
    const float* __restrict__ Ws, const float* __restrict__ cb,
    float* __restrict__ Aq, float* __restrict__ Av,
    float* __restrict__ Bk, float* __restrict__ AGG,
    int N)
{
    __shared__ __attribute__((aligned(16))) float xs[64 * (IN + 1)];
    __shared__ __attribute__((aligned(16))) float st[64 * 68];
    const int tid = threadIdx.x;
    const int n0 = blockIdx.x * 64;
    const int nn = min(64, N - n0);

    for (int idx = tid; idx < 64 * IN; idx += 256) {
        int r = idx / IN, c = idx - r * IN;
        int n = n0 + r;
        xs[r * (IN + 1) + c] = (r < nn) ? x[(size_t)n * IN + c] : 0.0f;
    }
    __syncthreads();

    const int lane = tid & 63;
    const int wave = __builtin_amdgcn_readfirstlane(tid >> 6);  // 0..3
    const int o0 = wave * 16;

    float ak[16], aq[16], av[16], as_[16];
#pragma unroll
    for (int j = 0; j < 16; ++j) {
        ak[j] = bk[o0 + j];
        aq[j] = bq[o0 + j];
        av[j] = bv[o0 + j];
        as_[j] = cb[o0 + j];
    }

    for (int k = 0; k < IN; ++k) {
        float xv = xs[lane * (IN + 1) + k];
        const float* __restrict__ wk = Wk + k * 64 + o0;   // wave-uniform
        const float* __restrict__ wq = Wq + k * 64 + o0;
        const float* __restrict__ wv = Wv + k * 64 + o0;
        const float* __restrict__ ws = Ws + k * 64 + o0;
#pragma unroll
        for (int j = 0; j < 16; ++j) {
            ak[j] = fmaf(xv, wk[j], ak[j]);
            aq[j] = fmaf(xv, wq[j], aq[j]);
            av[j] = fmaf(xv, wv[j], av[j]);
            as_[j] = fmaf(xv, ws[j], as_[j]);
        }
    }

    // stage acc -> LDS (transpose) -> coalesced float4 row stores
#define DUMP(ARR, DST)                                                        \
    do {                                                                      \
        __syncthreads();                                                      \
        _Pragma("unroll") for (int j = 0; j < 16; ++j)                        \
            st[lane * 68 + o0 + j] = ARR[j];                                  \
        __syncthreads();                                                      \
        int r = tid >> 2, cbv = (tid & 3) * 16;                               \
        if (r < nn) {                                                         \
            _Pragma("unroll") for (int i = 0; i < 4; ++i) {                   \
                *(float4*)&DST[((size_t)(n0 + r)) * 64 + cbv + 4 * i] =       \
                    *(float4*)&st[r * 68 + cbv + 4 * i];                      \
            }                                                                 \
        }                                                                     \
    } while (0)

    DUMP(ak, Bk);
    DUMP(aq, Aq);
    DUMP(av, Av);
    DUMP(as_, AGG);
#undef DUMP
}

// ---------------------------------------------------------------------------
// Edge bucketing (dst >> 7): histogram -> scan -> stable-ish scatter.
// ---------------------------------------------------------------------------
__global__ __launch_bounds__(256) void hist_kernel(
    const int* __restrict__ ei, int* __restrict__ bcount, int E, int NB)
{
    __shared__ int h[1024];
    for (int i = threadIdx.x; i < 1024; i += 256) h[i] = 0;
    __syncthreads();
    int t = blockIdx.x * 256 + threadIdx.x;
    int T = gridDim.x * 256;
    for (int e = t; e < E; e += T) atomicAdd(&h[ei[E + e] >> 7], 1);
    __syncthreads();
    for (int i = threadIdx.x; i < NB; i += 256)
        if (h[i]) atomicAdd(&bcount[i], h[i]);
}

__global__ __launch_bounds__(1024) void scan_kernel(
    const int* __restrict__ bcount, int* __restrict__ bstart,
    int* __restrict__ bcursor, int NB)
{
    __shared__ int sc[1024];
    int t = threadIdx.x;
    int c = (t < NB) ? bcount[t] : 0;
    sc[t] = c;
    __syncthreads();
    for (int off = 1; off < 1024; off <<= 1) {
        int v = (t >= off) ? sc[t - off] : 0;
        __syncthreads();
        sc[t] += v;
        __syncthreads();
    }
    if (t < NB) {
        int excl = sc[t] - c;
        bstart[t] = excl;
        bcursor[t] = excl;
    }
    if (t == NB - 1) bstart[NB] = sc[t];
}

__global__ __launch_bounds__(256) void scatter_kernel(
    const int* __restrict__ ei, int* __restrict__ bcursor,
    int* __restrict__ EP, int E, int NB)
{
    __shared__ int h[1024];
    const int chunk = (E + gridDim.x - 1) / gridDim.x;
    const int e0 = blockIdx.x * chunk;
    const int e1 = min(E, e0 + chunk);

    for (int i = threadIdx.x; i < 1024; i += 256) h[i] = 0;
    __syncthreads();
    for (int e = e0 + threadIdx.x; e < e1; e += 256)
        atomicAdd(&h[ei[E + e] >> 7], 1);
    __syncthreads();
    for (int b = threadIdx.x; b < NB; b += 256) {
        int cnt = h[b];
        h[b] = cnt ? atomicAdd(&bcursor[b], cnt) : 0;
    }
    __syncthreads();
    for (int e = e0 + threadIdx.x; e < e1; e += 256) {
        int d = ei[E + e];
        int b = d >> 7;
        int pos = atomicAdd(&h[b], 1);
        EP[pos] = (ei[e] << 7) | (d & 127);
    }
}

// ---------------------------------------------------------------------------
// Aggregation: block b owns dst nodes [b*128, b*128+128). LDS accumulate with
// ds_add_f32 (no global atomics), then epilogue fuses: AGG = sigmoid(preinit +
// acc), per-channel sum/sumsq partials -> 64 global atomics per block.
// ---------------------------------------------------------------------------
__global__ __launch_bounds__(256) void agg_kernel(
    const int* __restrict__ EP, const int* __restrict__ bstart,
    const float* __restrict__ Aq, const float* __restrict__ Av,
    const float* __restrict__ Bk,
    float* __restrict__ AGG, float* __restrict__ stats, int N)
{
    __shared__ float accs[128 * 64];
    __shared__ float red1[4][64], red2[4][64];
    const int tid = threadIdx.x;
    const int lane = tid & 63;
    const int w = __builtin_amdgcn_readfirstlane(tid >> 6);
    const int b = blockIdx.x;
    const int base = b * 128;

    for (int i = tid; i < 128 * 64; i += 256) accs[i] = 0.0f;
    __syncthreads();

    const int start = bstart[b], end = bstart[b + 1];

    int e = start + w;
    while (e + 4 < end) {
        int ep0 = EP[e], ep1 = EP[e + 4];
        int s0 = ep0 >> 7, d0 = ep0 & 127;
        int s1 = ep1 >> 7, d1 = ep1 & 127;
        float q0 = Aq[(size_t)s0 * 64 + lane];
        float v0 = Av[(size_t)s0 * 64 + lane];
        float q1 = Aq[(size_t)s1 * 64 + lane];
        float v1 = Av[(size_t)s1 * 64 + lane];
        float k0 = Bk[(size_t)(base + d0) * 64 + lane];
        float k1 = Bk[(size_t)(base + d1) * 64 + lane];
        float m0 = sigmoidf_(k0 + q0) * v0;
        float m1 = sigmoidf_(k1 + q1) * v1;
        atomicAdd(&accs[d0 * 64 + lane], m0);
        atomicAdd(&accs[d1 * 64 + lane], m1);
        e += 8;
    }
    while (e < end) {
        int ep = EP[e];
        int sr = ep >> 7, dl = ep & 127;
        float q = Aq[(size_t)sr * 64 + lane];
        float v = Av[(size_t)sr * 64 + lane];
        float kk = Bk[(size_t)(base + dl) * 64 + lane];
        atomicAdd(&accs[dl * 64 + lane], sigmoidf_(kk + q) * v);
        e += 4;
    }
    __syncthreads();

    // epilogue: sigmoid(preinit + acc) in place + channel stats
    const int nn = min(128, N - base);
    float s1a = 0.0f, s2a = 0.0f;
    for (int i = tid; i < nn * 64; i += 256) {
        float val = AGG[(size_t)base * 64 + i] + accs[i];
        float y = sigmoidf_(val);
        AGG[(size_t)base * 64 + i] = y;
        s1a += y;
        s2a += y * y;
    }
    const int rg = tid >> 6;
    red1[rg][lane] = s1a;
    red2[rg][lane] = s2a;
    __syncthreads();
    if (tid < 64) {
        float a = red1[0][lane] + red1[1][lane] + red1[2][lane] + red1[3][lane];
        float c = red2[0][lane] + red2[1][lane] + red2[2][lane] + red2[3][lane];
        atomicAdd(&stats[lane], a);
        atomicAdd(&stats[64 + lane], c);
    }
}

// ---------------------------------------------------------------------------
// BN-normalize in place + per-graph readout sums (run-length + atomic flush).
// ---------------------------------------------------------------------------
__global__ __launch_bounds__(256) void norm_kernel(
    float* __restrict__ Y, const float* __restrict__ stats,
    const float* __restrict__ g, const float* __restrict__ be,
    const int* __restrict__ batch, float* __restrict__ gsum,
    int N, float invN)
{
    const int lane = threadIdx.x & 63;
    const int gw = (int)((blockIdx.x * blockDim.x + threadIdx.x) >> 6);
    const int NW = (gridDim.x * blockDim.x) >> 6;
    const int chunk = (N + NW - 1) / NW;
    const int nA = gw * chunk;
    const int nB = min(N, nA + chunk);

    float m = stats[lane] * invN;
    float var = stats[64 + lane] * invN - m * m;
    float rs = rsqrtf(var + EPS) * g[lane];
    float bb = be[lane];

    float acc = 0.0f;
    int cur = -1;
    for (int n = nA; n < nB; ++n) {
        int gi = __builtin_amdgcn_readfirstlane(batch[n]);
        float y = Y[(size_t)n * 64 + lane];
        float v = (y - m) * rs + bb;
        Y[(size_t)n * 64 + lane] = v;   // in place: becomes next-layer input
        if (gi != cur) {
            if (cur >= 0) atomicAdd(&gsum[cur * 64 + lane], acc);
            acc = 0.0f;
            cur = gi;
        }
        acc += v;
    }
    if (cur >= 0) atomicAdd(&gsum[cur * 64 + lane], acc);
}

__global__ __launch_bounds__(256) void counts_kernel(
    const int* __restrict__ batch, float* __restrict__ counts, int N)
{
    const int t = blockIdx.x * blockDim.x + threadIdx.x;
    const int T = gridDim.x * blockDim.x;
    const int chunk = (N + T - 1) / T;
    const int a = t * chunk;
    const int b = min(N, a + chunk);
    int cur = -1;
    float c = 0.0f;
    for (int n = a; n < b; ++n) {
        int gi = batch[n];
        if (gi != cur) {
            if (cur >= 0) atomicAdd(&counts[cur], c);
            cur = gi;
            c = 0.0f;
        }
        c += 1.0f;
    }
    if (cur >= 0) atomicAdd(&counts[cur], c);
}

// ---------------------------------------------------------------------------
// Head
// ---------------------------------------------------------------------------
__global__ __launch_bounds__(128) void head1_kernel(
    const float* __restrict__ gsum0, const float* __restrict__ gsum1,
    const float* __restrict__ counts,
    const float* __restrict__ Wh0, const float* __restrict__ bh0,
    float* __restrict__ t0, float* __restrict__ hstat0)
{
    const int gr = blockIdx.x;
    const int o = threadIdx.x;
    __shared__ float feat[256];
    float cnt = fmaxf(counts[gr], 1.0f);
    float inv = __fdividef(1.0f, cnt);
    if (o < 64) {
        float s = gsum0[gr * 64 + o];
        feat[o] = s * inv;
        feat[128 + o] = s;
    } else {
        int c = o - 64;
        float s = gsum1[gr * 64 + c];
        feat[64 + c] = s * inv;
        feat[192 + c] = s;
    }
    __syncthreads();
    float acc = bh0[o];
    for (int j = 0; j < 256; ++j) acc = fmaf(feat[j], Wh0[j * 128 + o], acc);
    float y = sigmoidf_(acc);
    t0[gr * 128 + o] = y;
    atomicAdd(&hstat0[o], y);
    atomicAdd(&hstat0[128 + o], y * y);
}

__global__ __launch_bounds__(64) void head2_kernel(
    const float* __restrict__ t0, const float* __restrict__ hstat0,
    const float* __restrict__ gh0, const float* __restrict__ beh0,
    const float* __restrict__ Wh1, const float* __restrict__ bh1,
    float* __restrict__ t1, float* __restrict__ hstat1)
{
    const int gr = blockIdx.x;
    const int o = threadIdx.x;
    __shared__ float bn0[128];
    const float invG = 1.0f / (float)N_GRAPHS;
    for (int j = o; j < 128; j += 64) {
        float m = hstat0[j] * invG;
        float v = hstat0[128 + j] * invG - m * m;
        bn0[j] = (t0[gr * 128 + j] - m) * rsqrtf(v + EPS) * gh0[j] + beh0[j];
    }
    __syncthreads();
    float acc = bh1[o];
    for (int j = 0; j < 128; ++j) acc = fmaf(bn0[j], Wh1[j * 64 + o], acc);
    float y = sigmoidf_(acc);
    t1[gr * 64 + o] = y;
    atomicAdd(&hstat1[o], y);
    atomicAdd(&hstat1[64 + o], y * y);
}

__global__ __launch_bounds__(64) void head3_kernel(
    const float* __restrict__ t1, const float* __restrict__ hstat1,
    const float* __restrict__ gh1, const float* __restrict__ beh1,
    const float* __restrict__ Wc, const float* __restrict__ bc,
    float* __restrict__ out)
{
    const int gr = blockIdx.x;
    const int o = threadIdx.x;
    const float invG = 1.0f / (float)N_GRAPHS;
    float m = hstat1[o] * invG;
    float v = hstat1[64 + o] * invG - m * m;
    float b = (t1[gr * 64 + o] - m) * rsqrtf(v + EPS) * gh1[o] + beh1[o];
    float p0 = b * Wc[o * 2];
    float p1 = b * Wc[o * 2 + 1];
#pragma unroll
    for (int off = 32; off > 0; off >>= 1) {
        p0 += __shfl_down(p0, off);
        p1 += __shfl_down(p1, off);
    }
    if (o == 0) {
        out[gr * 2] = p0 + bc[0];
        out[gr * 2 + 1] = p1 + bc[1];
    }
}

// ---------------------------------------------------------------------------
extern "C" void kernel_launch(void* const* d_in, const int* in_sizes, int n_in,
                              void* d_out, int out_size, void* d_ws, size_t ws_size,
                              hipStream_t stream)
{
    const float* x     = (const float*)d_in[0];
    const int*   ei    = (const int*)d_in[1];
    const int*   batch = (const int*)d_in[2];
    const int N = in_sizes[2];
    const int E = in_sizes[1] / 2;
    const int NB = (N + 127) / 128;

    const float *Wk0 = (const float*)d_in[3],  *bk0 = (const float*)d_in[4];
    const float *Wq0 = (const float*)d_in[5],  *bq0 = (const float*)d_in[6];
    const float *Wv0 = (const float*)d_in[7],  *bv0 = (const float*)d_in[8];
    const float *Ws0 = (const float*)d_in[9],  *cb0 = (const float*)d_in[10];
    const float *g0  = (const float*)d_in[11], *be0 = (const float*)d_in[12];
    const float *Wk1 = (const float*)d_in[13], *bk1 = (const float*)d_in[14];
    const float *Wq1 = (const float*)d_in[15], *bq1 = (const float*)d_in[16];
    const float *Wv1 = (const float*)d_in[17], *bv1 = (const float*)d_in[18];
    const float *Ws1 = (const float*)d_in[19], *cb1 = (const float*)d_in[20];
    const float *g1  = (const float*)d_in[21], *be1 = (const float*)d_in[22];
    const float *Wh0 = (const float*)d_in[23], *bh0 = (const float*)d_in[24];
    const float *gh0 = (const float*)d_in[25], *beh0 = (const float*)d_in[26];
    const float *Wh1 = (const float*)d_in[27], *bh1 = (const float*)d_in[28];
    const float *gh1 = (const float*)d_in[29], *beh1 = (const float*)d_in[30];
    const float *Wc  = (const float*)d_in[31], *bc  = (const float*)d_in[32];

    float* ws = (float*)d_ws;
    float* Aq   = ws;                     // N*64
    float* Av   = Aq + (size_t)N * 64;    // N*64
    float* Bk   = Av + (size_t)N * 64;    // N*64
    float* AGG  = Bk + (size_t)N * 64;    // N*64 (preinit -> y -> BN out, in place)
    int*   EP      = (int*)(AGG + (size_t)N * 64);  // E
    int*   bstart  = EP + E;              // NB+1
    int*   bcursor = bstart + NB + 1;     // NB
    int*   bcount  = bcursor + NB;        // NB   <-- zero zone starts here
    float* gsum0  = (float*)(bcount + NB);  // 128*64
    float* gsum1  = gsum0 + 128 * 64;     // 128*64
    float* counts = gsum1 + 128 * 64;     // 128
    float* stats0 = counts + 128;         // 128
    float* stats1 = stats0 + 128;         // 128
    float* hstat0 = stats1 + 128;         // 256
    float* hstat1 = hstat0 + 256;         // 128
    size_t zbytes = (size_t)NB * sizeof(int) +
                    (size_t)(128 * 64 * 2 + 128 * 3 + 256 + 128) * sizeof(float);
    float* t0 = hstat1 + 128;             // 128*128
    float* t1 = t0 + 128 * 128;           // 128*64

    hipMemsetAsync(bcount, 0, zbytes, stream);

    // ---- edge bucketing (shared by both layers) ----
    hist_kernel<<<128, 256, 0, stream>>>(ei, bcount, E, NB);
    scan_kernel<<<1, 1024, 0, stream>>>(bcount, bstart, bcursor, NB);
    scatter_kernel<<<256, 256, 0, stream>>>(ei, bcursor, EP, E, NB);

    counts_kernel<<<16, 256, 0, stream>>>(batch, counts, N);

    const int projBlocks = (N + 63) / 64;

    // ---- layer 0 ----
    proj_kernel<128><<<projBlocks, 256, 0, stream>>>(
        x, Wk0, bk0, Wq0, bq0, Wv0, bv0, Ws0, cb0, Aq, Av, Bk, AGG, N);
    agg_kernel<<<NB, 256, 0, stream>>>(EP, bstart, Aq, Av, Bk, AGG, stats0, N);
    norm_kernel<<<1024, 256, 0, stream>>>(AGG, stats0, g0, be0, batch, gsum0,
                                          N, 1.0f / (float)N);

    // ---- layer 1 (AGG doubles as X1) ----
    proj_kernel<64><<<projBlocks, 256, 0, stream>>>(
        AGG, Wk1, bk1, Wq1, bq1, Wv1, bv1, Ws1, cb1, Aq, Av, Bk, AGG, N);
    agg_kernel<<<NB, 256, 0, stream>>>(EP, bstart, Aq, Av, Bk, AGG, stats1, N);
    norm_kernel<<<1024, 256, 0, stream>>>(AGG, stats1, g1, be1, batch, gsum1,
                                          N, 1.0f / (float)N);

    // ---- head ----
    head1_kernel<<<128, 128, 0, stream>>>(gsum0, gsum1, counts, Wh0, bh0, t0, hstat0);
    head2_kernel<<<128, 64, 0, stream>>>(t0, hstat0, gh0, beh0, Wh1, bh1, t1, hstat1);
    head3_kernel<<<128, 64, 0, stream>>>(t1, hstat1, gh1, beh1, Wc, bc, (float*)d_out);
}

// Round 3
// 1009.815 us; speedup vs baseline: 1.5210x; 1.5210x over previous
//
#include <hip/hip_runtime.h>
#include <math.h>

#define EPS 1e-5f
#define N_GRAPHS 128

__device__ __forceinline__ float sigmoidf_(float x) {
    return __fdividef(1.0f, 1.0f + __expf(-x));
}

// ---------------------------------------------------------------------------
// Projection kernel: one 64-node tile per block; all 4 projections fused in a
// single k-loop (1 LDS read -> 64 FMA with wave-uniform scalar weight loads).
// Outputs staged through LDS, stored as coalesced float4 row writes.
// x may alias AGG (layer 1 in-place): safe, rows staged to LDS first and each
// block writes only its own rows.
// ---------------------------------------------------------------------------
template <int IN>
__global__ __launch_bounds__(256) void proj_kernel(
    const float* __restrict__ x,
    const float* __restrict__ Wk, const float* __restrict__ bk,
    const float* __restrict__ Wq, const float* __restrict__ bq,
    const float* __restrict__ Wv, const float* __restrict__ bv,
    const float* __restrict__ Ws, const float* __restrict__ cb,
    float* __restrict__ Aq, float* __restrict__ Av,
    float* __restrict__ Bk, float* __restrict__ AGG,
    int N)
{
    __shared__ __attribute__((aligned(16))) float xs[64 * (IN + 1)];
    __shared__ __attribute__((aligned(16))) float st[64 * 68];
    const int tid = threadIdx.x;
    const int n0 = blockIdx.x * 64;
    const int nn = min(64, N - n0);

    for (int idx = tid; idx < 64 * IN; idx += 256) {
        int r = idx / IN, c = idx - r * IN;
        int n = n0 + r;
        xs[r * (IN + 1) + c] = (r < nn) ? x[(size_t)n * IN + c] : 0.0f;
    }
    __syncthreads();

    const int lane = tid & 63;
    const int wave = __builtin_amdgcn_readfirstlane(tid >> 6);  // 0..3
    const int o0 = wave * 16;

    float ak[16], aq[16], av[16], as_[16];
#pragma unroll
    for (int j = 0; j < 16; ++j) {
        ak[j] = bk[o0 + j];
        aq[j] = bq[o0 + j];
        av[j] = bv[o0 + j];
        as_[j] = cb[o0 + j];
    }

    for (int k = 0; k < IN; ++k) {
        float xv = xs[lane * (IN + 1) + k];
        const float* __restrict__ wk = Wk + k * 64 + o0;   // wave-uniform
        const float* __restrict__ wq = Wq + k * 64 + o0;
        const float* __restrict__ wv = Wv + k * 64 + o0;
        const float* __restrict__ ws = Ws + k * 64 + o0;
#pragma unroll
        for (int j = 0; j < 16; ++j) {
            ak[j] = fmaf(xv, wk[j], ak[j]);
            aq[j] = fmaf(xv, wq[j], aq[j]);
            av[j] = fmaf(xv, wv[j], av[j]);
            as_[j] = fmaf(xv, ws[j], as_[j]);
        }
    }

#define DUMP(ARR, DST)                                                        \
    do {                                                                      \
        __syncthreads();                                                      \
        _Pragma("unroll") for (int j = 0; j < 16; ++j)                        \
            st[lane * 68 + o0 + j] = ARR[j];                                  \
        __syncthreads();                                                      \
        int r = tid >> 2, cbv = (tid & 3) * 16;                               \
        if (r < nn) {                                                         \
            _Pragma("unroll") for (int i = 0; i < 4; ++i) {                   \
                *(float4*)&DST[((size_t)(n0 + r)) * 64 + cbv + 4 * i] =       \
                    *(float4*)&st[r * 68 + cbv + 4 * i];                      \
            }                                                                 \
        }                                                                     \
    } while (0)

    DUMP(ak, Bk);
    DUMP(aq, Aq);
    DUMP(av, Av);
    DUMP(as_, AGG);
#undef DUMP
}

// ---------------------------------------------------------------------------
// CSR build: degree histogram -> 2-level exclusive scan -> scatter.
// ---------------------------------------------------------------------------
__global__ __launch_bounds__(256) void deg_kernel(
    const int* __restrict__ ei, int* __restrict__ deg, int E)
{
    int t = blockIdx.x * 256 + threadIdx.x;
    int T = gridDim.x * 256;
    for (int e = t; e < E; e += T) atomicAdd(&deg[ei[E + e]], 1);
}

// inclusive scan within 1024-element chunks; psum[b] = chunk total
__global__ __launch_bounds__(256) void scan1_kernel(
    const int* __restrict__ deg, int* __restrict__ rp1loc,
    int* __restrict__ psum, int N)
{
    __shared__ int s[256];
    const int b = blockIdx.x;
    const int base = b * 1024;
    const int t = threadIdx.x;
    int v[4], sum = 0;
#pragma unroll
    for (int i = 0; i < 4; ++i) {
        int idx = base + t * 4 + i;
        v[i] = (idx < N) ? deg[idx] : 0;
        sum += v[i];
    }
    s[t] = sum;
    __syncthreads();
    for (int off = 1; off < 256; off <<= 1) {
        int x = (t >= off) ? s[t - off] : 0;
        __syncthreads();
        s[t] += x;
        __syncthreads();
    }
    int run = s[t] - sum;   // exclusive prefix within chunk
#pragma unroll
    for (int i = 0; i < 4; ++i) {
        run += v[i];
        int idx = base + t * 4 + i;
        if (idx < N) rp1loc[idx] = run;   // chunk-local inclusive scan
    }
    if (t == 255) psum[b] = s[255];
}

// single-block exclusive scan of psum (NBLK <= 256)
__global__ __launch_bounds__(256) void scan2_kernel(int* __restrict__ psum, int NBLK)
{
    __shared__ int s[256];
    int t = threadIdx.x;
    int c = (t < NBLK) ? psum[t] : 0;
    s[t] = c;
    __syncthreads();
    for (int off = 1; off < 256; off <<= 1) {
        int x = (t >= off) ? s[t - off] : 0;
        __syncthreads();
        s[t] += x;
        __syncthreads();
    }
    if (t < NBLK) psum[t] = s[t] - c;
}

// finalize rowptr + cursor (no read-after-write hazards: both derive from
// rp1loc/psum only)
__global__ __launch_bounds__(256) void scan3_kernel(
    const int* __restrict__ rp1loc, const int* __restrict__ psum,
    int* __restrict__ rowptr, int* __restrict__ cursor, int N)
{
    int t = blockIdx.x * 256 + threadIdx.x;
    int T = gridDim.x * 256;
    for (int i = t; i < N; i += T) {
        rowptr[i + 1] = rp1loc[i] + psum[i >> 10];
        cursor[i] = (i == 0) ? 0 : rp1loc[i - 1] + psum[(i - 1) >> 10];
    }
    if (t == 0) rowptr[0] = 0;
}

__global__ __launch_bounds__(256) void scatter_kernel(
    const int* __restrict__ ei, int* __restrict__ cursor,
    int* __restrict__ col, int E)
{
    int t = blockIdx.x * 256 + threadIdx.x;
    int T = gridDim.x * 256;
    for (int e = t; e < E; e += T) {
        int d = ei[E + e];
        int pos = atomicAdd(&cursor[d], 1);
        col[pos] = ei[e];
    }
}

// ---------------------------------------------------------------------------
// Aggregation v3: one dst node per wave (grid-stride). lane = channel.
// src indices loaded coalesced (col[r0+lane]), broadcast via shfl; gathers
// unrolled 4-deep (8 independent 256B loads in flight). Zero atomics in the
// main loop. Epilogue fuses sigmoid + BN channel stats.
// ---------------------------------------------------------------------------
__global__ __launch_bounds__(256) void agg_kernel(
    const int* __restrict__ rowptr, const int* __restrict__ col,
    const float* __restrict__ Aq, const float* __restrict__ Av,
    const float* __restrict__ Bk,
    float* __restrict__ AGG, float* __restrict__ stats, int N)
{
    const int tid = threadIdx.x;
    const int lane = tid & 63;
    const int gw = __builtin_amdgcn_readfirstlane(
        (int)((blockIdx.x * blockDim.x + tid) >> 6));
    const int NW = (gridDim.x * blockDim.x) >> 6;

    float st1 = 0.0f, st2 = 0.0f;
    for (int n = gw; n < N; n += NW) {
        int r0 = rowptr[n], r1 = rowptr[n + 1];
        float kk = Bk[(size_t)n * 64 + lane];
        float acc = AGG[(size_t)n * 64 + lane];   // preinit x@Ws+cb
        int e = r0;
        while (e < r1) {
            int cnt = min(64, r1 - e);
            int my = (lane < cnt) ? col[e + lane] : 0;
            int j = 0;
            for (; j + 4 <= cnt; j += 4) {
                int s0 = __shfl(my, j);
                int s1 = __shfl(my, j + 1);
                int s2 = __shfl(my, j + 2);
                int s3 = __shfl(my, j + 3);
                float q0 = Aq[(size_t)s0 * 64 + lane];
                float v0 = Av[(size_t)s0 * 64 + lane];
                float q1 = Aq[(size_t)s1 * 64 + lane];
                float v1 = Av[(size_t)s1 * 64 + lane];
                float q2 = Aq[(size_t)s2 * 64 + lane];
                float v2 = Av[(size_t)s2 * 64 + lane];
                float q3 = Aq[(size_t)s3 * 64 + lane];
                float v3 = Av[(size_t)s3 * 64 + lane];
                acc += sigmoidf_(kk + q0) * v0;
                acc += sigmoidf_(kk + q1) * v1;
                acc += sigmoidf_(kk + q2) * v2;
                acc += sigmoidf_(kk + q3) * v3;
            }
            for (; j < cnt; ++j) {
                int s0 = __shfl(my, j);
                float q0 = Aq[(size_t)s0 * 64 + lane];
                float v0 = Av[(size_t)s0 * 64 + lane];
                acc += sigmoidf_(kk + q0) * v0;
            }
            e += cnt;
        }
        float y = sigmoidf_(acc);
        AGG[(size_t)n * 64 + lane] = y;
        st1 += y;
        st2 += y * y;
    }

    __shared__ float red1[4][64], red2[4][64];
    const int w = tid >> 6;
    red1[w][lane] = st1;
    red2[w][lane] = st2;
    __syncthreads();
    if (tid < 64) {
        float a = red1[0][lane] + red1[1][lane] + red1[2][lane] + red1[3][lane];
        float c = red2[0][lane] + red2[1][lane] + red2[2][lane] + red2[3][lane];
        atomicAdd(&stats[lane], a);
        atomicAdd(&stats[64 + lane], c);
    }
}

// ---------------------------------------------------------------------------
// BN-normalize in place + per-graph readout sums (run-length + atomic flush).
// ---------------------------------------------------------------------------
__global__ __launch_bounds__(256) void norm_kernel(
    float* __restrict__ Y, const float* __restrict__ stats,
    const float* __restrict__ g, const float* __restrict__ be,
    const int* __restrict__ batch, float* __restrict__ gsum,
    int N, float invN)
{
    const int lane = threadIdx.x & 63;
    const int gw = (int)((blockIdx.x * blockDim.x + threadIdx.x) >> 6);
    const int NW = (gridDim.x * blockDim.x) >> 6;
    const int chunk = (N + NW - 1) / NW;
    const int nA = gw * chunk;
    const int nB = min(N, nA + chunk);

    float m = stats[lane] * invN;
    float var = stats[64 + lane] * invN - m * m;
    float rs = rsqrtf(var + EPS) * g[lane];
    float bb = be[lane];

    float acc = 0.0f;
    int cur = -1;
    for (int n = nA; n < nB; ++n) {
        int gi = __builtin_amdgcn_readfirstlane(batch[n]);
        float y = Y[(size_t)n * 64 + lane];
        float v = (y - m) * rs + bb;
        Y[(size_t)n * 64 + lane] = v;   // in place: becomes next-layer input
        if (gi != cur) {
            if (cur >= 0) atomicAdd(&gsum[cur * 64 + lane], acc);
            acc = 0.0f;
            cur = gi;
        }
        acc += v;
    }
    if (cur >= 0) atomicAdd(&gsum[cur * 64 + lane], acc);
}

__global__ __launch_bounds__(256) void counts_kernel(
    const int* __restrict__ batch, float* __restrict__ counts, int N)
{
    const int t = blockIdx.x * blockDim.x + threadIdx.x;
    const int T = gridDim.x * blockDim.x;
    const int chunk = (N + T - 1) / T;
    const int a = t * chunk;
    const int b = min(N, a + chunk);
    int cur = -1;
    float c = 0.0f;
    for (int n = a; n < b; ++n) {
        int gi = batch[n];
        if (gi != cur) {
            if (cur >= 0) atomicAdd(&counts[cur], c);
            cur = gi;
            c = 0.0f;
        }
        c += 1.0f;
    }
    if (cur >= 0) atomicAdd(&counts[cur], c);
}

// ---------------------------------------------------------------------------
// Head
// ---------------------------------------------------------------------------
__global__ __launch_bounds__(128) void head1_kernel(
    const float* __restrict__ gsum0, const float* __restrict__ gsum1,
    const float* __restrict__ counts,
    const float* __restrict__ Wh0, const float* __restrict__ bh0,
    float* __restrict__ t0, float* __restrict__ hstat0)
{
    const int gr = blockIdx.x;
    const int o = threadIdx.x;
    __shared__ float feat[256];
    float cnt = fmaxf(counts[gr], 1.0f);
    float inv = __fdividef(1.0f, cnt);
    if (o < 64) {
        float s = gsum0[gr * 64 + o];
        feat[o] = s * inv;
        feat[128 + o] = s;
    } else {
        int c = o - 64;
        float s = gsum1[gr * 64 + c];
        feat[64 + c] = s * inv;
        feat[192 + c] = s;
    }
    __syncthreads();
    float acc = bh0[o];
    for (int j = 0; j < 256; ++j) acc = fmaf(feat[j], Wh0[j * 128 + o], acc);
    float y = sigmoidf_(acc);
    t0[gr * 128 + o] = y;
    atomicAdd(&hstat0[o], y);
    atomicAdd(&hstat0[128 + o], y * y);
}

__global__ __launch_bounds__(64) void head2_kernel(
    const float* __restrict__ t0, const float* __restrict__ hstat0,
    const float* __restrict__ gh0, const float* __restrict__ beh0,
    const float* __restrict__ Wh1, const float* __restrict__ bh1,
    float* __restrict__ t1, float* __restrict__ hstat1)
{
    const int gr = blockIdx.x;
    const int o = threadIdx.x;
    __shared__ float bn0[128];
    const float invG = 1.0f / (float)N_GRAPHS;
    for (int j = o; j < 128; j += 64) {
        float m = hstat0[j] * invG;
        float v = hstat0[128 + j] * invG - m * m;
        bn0[j] = (t0[gr * 128 + j] - m) * rsqrtf(v + EPS) * gh0[j] + beh0[j];
    }
    __syncthreads();
    float acc = bh1[o];
    for (int j = 0; j < 128; ++j) acc = fmaf(bn0[j], Wh1[j * 64 + o], acc);
    float y = sigmoidf_(acc);
    t1[gr * 64 + o] = y;
    atomicAdd(&hstat1[o], y);
    atomicAdd(&hstat1[64 + o], y * y);
}

__global__ __launch_bounds__(64) void head3_kernel(
    const float* __restrict__ t1, const float* __restrict__ hstat1,
    const float* __restrict__ gh1, const float* __restrict__ beh1,
    const float* __restrict__ Wc, const float* __restrict__ bc,
    float* __restrict__ out)
{
    const int gr = blockIdx.x;
    const int o = threadIdx.x;
    const float invG = 1.0f / (float)N_GRAPHS;
    float m = hstat1[o] * invG;
    float v = hstat1[64 + o] * invG - m * m;
    float b = (t1[gr * 64 + o] - m) * rsqrtf(v + EPS) * gh1[o] + beh1[o];
    float p0 = b * Wc[o * 2];
    float p1 = b * Wc[o * 2 + 1];
#pragma unroll
    for (int off = 32; off > 0; off >>= 1) {
        p0 += __shfl_down(p0, off);
        p1 += __shfl_down(p1, off);
    }
    if (o == 0) {
        out[gr * 2] = p0 + bc[0];
        out[gr * 2 + 1] = p1 + bc[1];
    }
}

// ---------------------------------------------------------------------------
extern "C" void kernel_launch(void* const* d_in, const int* in_sizes, int n_in,
                              void* d_out, int out_size, void* d_ws, size_t ws_size,
                              hipStream_t stream)
{
    const float* x     = (const float*)d_in[0];
    const int*   ei    = (const int*)d_in[1];
    const int*   batch = (const int*)d_in[2];
    const int N = in_sizes[2];
    const int E = in_sizes[1] / 2;
    const int NCHUNK = (N + 1023) / 1024;   // scan chunks (<=256)

    const float *Wk0 = (const float*)d_in[3],  *bk0 = (const float*)d_in[4];
    const float *Wq0 = (const float*)d_in[5],  *bq0 = (const float*)d_in[6];
    const float *Wv0 = (const float*)d_in[7],  *bv0 = (const float*)d_in[8];
    const float *Ws0 = (const float*)d_in[9],  *cb0 = (const float*)d_in[10];
    const float *g0  = (const float*)d_in[11], *be0 = (const float*)d_in[12];
    const float *Wk1 = (const float*)d_in[13], *bk1 = (const float*)d_in[14];
    const float *Wq1 = (const float*)d_in[15], *bq1 = (const float*)d_in[16];
    const float *Wv1 = (const float*)d_in[17], *bv1 = (const float*)d_in[18];
    const float *Ws1 = (const float*)d_in[19], *cb1 = (const float*)d_in[20];
    const float *g1  = (const float*)d_in[21], *be1 = (const float*)d_in[22];
    const float *Wh0 = (const float*)d_in[23], *bh0 = (const float*)d_in[24];
    const float *gh0 = (const float*)d_in[25], *beh0 = (const float*)d_in[26];
    const float *Wh1 = (const float*)d_in[27], *bh1 = (const float*)d_in[28];
    const float *gh1 = (const float*)d_in[29], *beh1 = (const float*)d_in[30];
    const float *Wc  = (const float*)d_in[31], *bc  = (const float*)d_in[32];

    float* ws = (float*)d_ws;
    float* Aq   = ws;                     // N*64
    float* Av   = Aq + (size_t)N * 64;    // N*64
    float* Bk   = Av + (size_t)N * 64;    // N*64
    float* AGG  = Bk + (size_t)N * 64;    // N*64 (preinit -> y -> BN out, in place)
    int*   col     = (int*)(AGG + (size_t)N * 64);  // E
    int*   rowptr  = col + E;             // N+1
    int*   rp1loc  = rowptr + N + 1;      // N
    int*   cursor  = rp1loc + N;          // N
    int*   psum    = cursor + N;          // 256
    int*   deg     = psum + 256;          // N    <-- zero zone starts here
    float* gsum0  = (float*)(deg + N);    // 128*64
    float* gsum1  = gsum0 + 128 * 64;     // 128*64
    float* counts = gsum1 + 128 * 64;     // 128
    float* stats0 = counts + 128;         // 128
    float* stats1 = stats0 + 128;         // 128
    float* hstat0 = stats1 + 128;         // 256
    float* hstat1 = hstat0 + 256;         // 128
    size_t zbytes = (size_t)N * sizeof(int) +
                    (size_t)(128 * 64 * 2 + 128 * 3 + 256 + 128) * sizeof(float);
    float* t0 = hstat1 + 128;             // 128*128
    float* t1 = t0 + 128 * 128;           // 128*64

    hipMemsetAsync(deg, 0, zbytes, stream);

    // ---- CSR build (shared by both layers) ----
    deg_kernel<<<256, 256, 0, stream>>>(ei, deg, E);
    scan1_kernel<<<NCHUNK, 256, 0, stream>>>(deg, rp1loc, psum, N);
    scan2_kernel<<<1, 256, 0, stream>>>(psum, NCHUNK);
    scan3_kernel<<<256, 256, 0, stream>>>(rp1loc, psum, rowptr, cursor, N);
    scatter_kernel<<<512, 256, 0, stream>>>(ei, cursor, col, E);

    counts_kernel<<<16, 256, 0, stream>>>(batch, counts, N);

    const int projBlocks = (N + 63) / 64;

    // ---- layer 0 ----
    proj_kernel<128><<<projBlocks, 256, 0, stream>>>(
        x, Wk0, bk0, Wq0, bq0, Wv0, bv0, Ws0, cb0, Aq, Av, Bk, AGG, N);
    agg_kernel<<<2048, 256, 0, stream>>>(rowptr, col, Aq, Av, Bk, AGG, stats0, N);
    norm_kernel<<<1024, 256, 0, stream>>>(AGG, stats0, g0, be0, batch, gsum0,
                                          N, 1.0f / (float)N);

    // ---- layer 1 (AGG doubles as X1) ----
    proj_kernel<64><<<projBlocks, 256, 0, stream>>>(
        AGG, Wk1, bk1, Wq1, bq1, Wv1, bv1, Ws1, cb1, Aq, Av, Bk, AGG, N);
    agg_kernel<<<2048, 256, 0, stream>>>(rowptr, col, Aq, Av, Bk, AGG, stats1, N);
    norm_kernel<<<1024, 256, 0, stream>>>(AGG, stats1, g1, be1, batch, gsum1,
                                          N, 1.0f / (float)N);

    // ---- head ----
    head1_kernel<<<128, 128, 0, stream>>>(gsum0, gsum1, counts, Wh0, bh0, t0, hstat0);
    head2_kernel<<<128, 64, 0, stream>>>(t0, hstat0, gh0, beh0, Wh1, bh1, t1, hstat1);
    head3_kernel<<<128, 64, 0, stream>>>(t1, hstat1, gh1, beh1, Wc, bc, (float*)d_out);
}